// Round 9
// baseline (143.080 us; speedup 1.0000x reference)
//
#include <hip/hip_runtime.h>
#include <hip/hip_bf16.h>

#define NB 8
#define NN 2048
#define NF 64      // in features
#define NP 64      // out features per head
#define NH 4
#define NHF 256    // NH*NP
#define LOG2E 1.4426950408889634f

typedef float f32x4 __attribute__((ext_vector_type(4)));
typedef short bf16x8 __attribute__((ext_vector_type(8)));
typedef short s16x4 __attribute__((ext_vector_type(4)));

// f32 -> bf16 bits, round-nearest-even
__device__ __forceinline__ short f2bf(float f) {
    unsigned u = __builtin_bit_cast(unsigned, f);
    unsigned r = (u + 0x7fffu + ((u >> 16) & 1u)) >> 16;
    return (short)r;
}

__device__ __forceinline__ float exp2_fast(float x) {
#if __has_builtin(__builtin_amdgcn_exp2f)
    return __builtin_amdgcn_exp2f(x);
#else
    float r;
    asm volatile("v_exp_f32 %0, %1\n\ts_nop 1" : "=v"(r) : "v"(x));
    return r;
#endif
}

__device__ __forceinline__ void async16(const void* g, void* l) {
    __builtin_amdgcn_global_load_lds(
        (const __attribute__((address_space(1))) void*)g,
        (__attribute__((address_space(3))) void*)l, 16, 0, 0);
}

// Full drain before barrier: required so LDS-DMA (global_load_lds) is complete
// before any wave crosses (R7 replay-race lesson).
#define DRAIN_BARRIER() do {                                                  \
        asm volatile("s_waitcnt vmcnt(0) lgkmcnt(0)" ::: "memory");           \
        __syncthreads();                                                      \
    } while (0)

// ---------------------------------------------------------------------------
// Kernel A1: s_out[b,h,n] = (x[b,n,:] . (W[h] @ a_out[h])) * LOG2E, same s_in.
// ---------------------------------------------------------------------------
__global__ __launch_bounds__(256) void gat_scores(
    const float* __restrict__ x, const float* __restrict__ W,
    const float* __restrict__ a_out, const float* __restrict__ a_in,
    float* __restrict__ s_out, float* __restrict__ s_in)
{
    __shared__ float co_lds[NH][NF];
    __shared__ float ci_lds[NH][NF];
    int tid = threadIdx.x;
    int h = tid >> 6, f = tid & 63;
    {
        float co = 0.f, ci = 0.f;
        const float* wrow = W + (h * NF + f) * NP;
        #pragma unroll 8
        for (int o = 0; o < NP; ++o) {
            float w = wrow[o];
            co = fmaf(w, a_out[h * NP + o], co);
            ci = fmaf(w, a_in[h * NP + o], ci);
        }
        co_lds[h][f] = co;
        ci_lds[h][f] = ci;
    }
    __syncthreads();
    int wid = tid >> 6, lane = tid & 63;
    float cov[NH], civ[NH];
    #pragma unroll
    for (int hh = 0; hh < NH; ++hh) { cov[hh] = co_lds[hh][lane]; civ[hh] = ci_lds[hh][lane]; }
    int base = blockIdx.x * 64 + wid * 16;     // global row in [0, B*N)
    for (int r = 0; r < 16; ++r) {
        int gn = base + r;
        float xv = x[(size_t)gn * NF + lane];
        #pragma unroll
        for (int hh = 0; hh < NH; ++hh) {
            float vo = xv * cov[hh];
            float vi = xv * civ[hh];
            #pragma unroll
            for (int s2 = 1; s2 < 64; s2 <<= 1) {
                vo += __shfl_xor(vo, s2, 64);
                vi += __shfl_xor(vi, s2, 64);
            }
            if (lane == 0) {
                int b = gn >> 11, n = gn & (NN - 1);
                s_out[((size_t)b * NH + hh) * NN + n] = vo * LOG2E;
                s_in [((size_t)b * NH + hh) * NN + n] = vi * LOG2E;
            }
        }
    }
}

// ---------------------------------------------------------------------------
// Kernel A2: featsT interleaved: element (feature o, node j) of head (b,h) at
// base(b,h) + (j>>3)*512 + o*8 + (j&7)  => V-frag loads are 256B-contiguous.
// ---------------------------------------------------------------------------
__global__ __launch_bounds__(256) void gat_feats(
    const float* __restrict__ x, const float* __restrict__ W,
    short* __restrict__ featsT)
{
    int blk = blockIdx.x;
    int nb = blk & 31;           // N/64 = 32
    int h  = (blk >> 5) & 3;
    int b  = blk >> 7;
    int tid = threadIdx.x, wid = tid >> 6, lane = tid & 63;
    int n0 = nb * 64 + wid * 16;
    int rA = lane & 15, g = lane >> 4;

    bf16x8 af[2];
    #pragma unroll
    for (int kk = 0; kk < 2; ++kk) {
        const float* xp = x + ((size_t)(b * NN) + n0 + rA) * NF + kk * 32 + g * 8;
        f32x4 x0 = *(const f32x4*)xp;
        f32x4 x1 = *(const f32x4*)(xp + 4);
        #pragma unroll
        for (int e = 0; e < 4; ++e) {
            af[kk][e]     = f2bf(x0[e]);
            af[kk][e + 4] = f2bf(x1[e]);
        }
    }
    f32x4 acc[4] = {};
    #pragma unroll
    for (int o = 0; o < 4; ++o) {
        #pragma unroll
        for (int kk = 0; kk < 2; ++kk) {
            bf16x8 bfv;
            #pragma unroll
            for (int e = 0; e < 8; ++e) {
                float wv = W[((size_t)h * NF + kk * 32 + g * 8 + e) * NP + o * 16 + rA];
                bfv[e] = f2bf(wv);
            }
            acc[o] = __builtin_amdgcn_mfma_f32_16x16x32_bf16(af[kk], bfv, acc[o], 0, 0, 0);
        }
    }
    size_t hb = (size_t)(b * NH + h) * NP * NN;
    int jq = n0 / 8 + (g >> 1);     // j>>3 for j = n0 + g*4
    int jr = (g & 1) * 4;           // j&7
    #pragma unroll
    for (int o = 0; o < 4; ++o) {
        s16x4 pk;
        pk[0] = f2bf(acc[o][0]);
        pk[1] = f2bf(acc[o][1]);
        pk[2] = f2bf(acc[o][2]);
        pk[3] = f2bf(acc[o][3]);
        *(s16x4*)(featsT + hb + (size_t)jq * 512 + (o * 16 + rA) * 8 + jr) = pk;
    }
}

// ---------------------------------------------------------------------------
// Kernel B (split): partial attention over half the j-range.
// Grid: B*(N/16)*2 = 2048 blocks x 256 thr -> 8 blocks/CU, 32 waves/CU target.
// Super-chunk = 128 j (8 per half), adj double-buffered (2 x 8 KB LDS).
// Staging: one async16 = 2 adj rows (lane<32 -> row R, lane>=32 -> row R+1);
// swizzle on global source block: (lane&31) ^ (row&7). Read: frag block
// (jg*2+c) ^ (r&7) within each 128B group. Partial numerator/denominator out.
// ---------------------------------------------------------------------------
__global__ __launch_bounds__(256)
__attribute__((amdgpu_waves_per_eu(8, 8)))
void gat_attn_part(
    const float* __restrict__ adj,     // [B,N,N]
    const short* __restrict__ featsT,  // interleaved
    const float* __restrict__ s_out,   // [B,H,N]  (prescaled by log2e)
    const float* __restrict__ s_in,    // [B,H,N]  (prescaled by log2e)
    float* __restrict__ part,          // [2,B,N,H*FP] partial numerators
    float* __restrict__ dpart)         // [2,B,H,N]  partial denominators
{
    __shared__ __align__(16) float adj_lds[2][2048];  // 2 x 8 KB (16 rows x 128 j)

    int blk = blockIdx.x;
    int b  = blk >> 8;
    int it = (blk >> 1) & 127;
    int jh = blk & 1;
    int i0 = it * 16;
    int j0 = jh << 10;            // 0 or 1024
    int tid = threadIdx.x;
    int h = tid >> 6;             // wave = head (wave-uniform)
    int lane = tid & 63;
    int r  = lane & 15;
    int jg = lane >> 4;

    // staging sources: call k covers rows h*4+2k (lanes 0-31) and +1 (32-63)
    const char* asrc[2];
    #pragma unroll
    for (int k = 0; k < 2; ++k) {
        int row = h * 4 + 2 * k + (lane >> 5);
        asrc[k] = (const char*)(adj + ((size_t)b * NN + i0 + row) * NN + j0)
                  + (((lane & 31) ^ (row & 7)) << 4);
    }

#define STAGE(BUF, SC) do {                                                   \
        _Pragma("unroll")                                                     \
        for (int k = 0; k < 2; ++k)                                           \
            async16(asrc[k] + (SC) * 512,                                     \
                    &adj_lds[BUF][(h * 4 + 2 * k) << 7]);                     \
    } while (0)

    STAGE(0, 0);

    float so = s_out[((size_t)b * NH + h) * NN + i0 + r];
    const float* sirow = s_in + ((size_t)b * NH + h) * NN + j0 + jg * 8;
    const short* vwave = featsT + (size_t)(b * NH + h) * NP * NN
                         + (size_t)j0 * 64 + jg * 512 + r * 8;
    int rsw = r & 7;
    int f0 = ((jg * 2)     ^ rsw) << 2;
    int f1 = ((jg * 2 + 1) ^ rsw) << 2;
    int rbase = r << 7;                   // row stride = 128 floats (512B)

    bf16x8 ones;
    #pragma unroll
    for (int e = 0; e < 8; ++e) ones[e] = (short)0x3F80;   // bf16 1.0

    DRAIN_BARRIER();

    f32x4 acc[4] = {};
    f32x4 acc4 = {};

#define KSTEP(S, KS, Q0, Q1, V0, V1, V2, V3) do {                             \
        const float* ap = ab + rbase + (S) * 64 + (KS) * 32;                  \
        f32x4 a0 = *(const f32x4*)(ap + f0);                                  \
        f32x4 a1 = *(const f32x4*)(ap + f1);                                  \
        bf16x8 af;                                                            \
        _Pragma("unroll")                                                     \
        for (int e = 0; e < 8; ++e) {                                         \
            float av = (e < 4) ? a0[e] : a1[e - 4];                           \
            float sv = (e < 4) ? Q0[e] : Q1[e - 4];                           \
            float t = so + sv;                                                \
            float lr = fmaxf(t, 0.2f * t);                                    \
            float arg = fmaf(av, LOG2E, lr);                                  \
            float pe_ = exp2_fast(arg);                                       \
            float p = (av != 0.f) ? pe_ : 0.f;                                \
            __hip_bfloat16 hbv = __float2bfloat16(p);                         \
            af[e] = (short)__builtin_bit_cast(unsigned short, hbv);           \
        }                                                                     \
        acc[0] = __builtin_amdgcn_mfma_f32_16x16x32_bf16(af, V0, acc[0], 0, 0, 0); \
        acc[1] = __builtin_amdgcn_mfma_f32_16x16x32_bf16(af, V1, acc[1], 0, 0, 0); \
        acc[2] = __builtin_amdgcn_mfma_f32_16x16x32_bf16(af, V2, acc[2], 0, 0, 0); \
        acc[3] = __builtin_amdgcn_mfma_f32_16x16x32_bf16(af, V3, acc[3], 0, 0, 0); \
        acc4   = __builtin_amdgcn_mfma_f32_16x16x32_bf16(af, ones, acc4, 0, 0, 0); \
    } while (0)

#define SUB(SC, S) do {                                                       \
        const short* vp = vwave + ((SC) * 8192 + (S) * 4096);                 \
        bf16x8 v00 = *(const bf16x8*)(vp);                                    \
        bf16x8 v01 = *(const bf16x8*)(vp + 128);                              \
        bf16x8 v02 = *(const bf16x8*)(vp + 256);                              \
        bf16x8 v03 = *(const bf16x8*)(vp + 384);                              \
        bf16x8 v10 = *(const bf16x8*)(vp + 2048);                             \
        bf16x8 v11 = *(const bf16x8*)(vp + 2048 + 128);                       \
        bf16x8 v12 = *(const bf16x8*)(vp + 2048 + 256);                       \
        bf16x8 v13 = *(const bf16x8*)(vp + 2048 + 384);                       \
        const float* sip = sirow + (SC) * 128 + (S) * 64;                     \
        f32x4 q00 = *(const f32x4*)(sip);                                     \
        f32x4 q01 = *(const f32x4*)(sip + 4);                                 \
        f32x4 q10 = *(const f32x4*)(sip + 32);                                \
        f32x4 q11 = *(const f32x4*)(sip + 36);                                \
        KSTEP(S, 0, q00, q01, v00, v01, v02, v03);                            \
        KSTEP(S, 1, q10, q11, v10, v11, v12, v13);                            \
    } while (0)

    for (int sc = 0; sc < 8; ++sc) {
        int cur = sc & 1;
        const float* ab = &adj_lds[cur][0];
        SUB(sc, 0);
        if (sc < 7) STAGE(cur ^ 1, sc + 1);
        SUB(sc, 1);
        DRAIN_BARRIER();
    }
#undef SUB
#undef KSTEP
#undef STAGE

    // write partial numerator / denominator
    #pragma unroll
    for (int reg = 0; reg < 4; ++reg) {
        int row = jg * 4 + reg;
        float* prow = part + (((size_t)jh * NB + b) * NN + i0 + row) * NHF + h * NP;
        #pragma unroll
        for (int o = 0; o < 4; ++o)
            prow[o * 16 + r] = acc[o][reg];
        if (r == 0)
            dpart[(((size_t)jh * NB + b) * NH + h) * NN + i0 + row] = acc4[reg];
    }
}

// ---------------------------------------------------------------------------
// Kernel C: combine halves: out = ELU((n0+n1)/(d0+d1) + bias).
// Grid: B*N*NHF/4/256 = 4096 blocks x 256 thr, float4 per thread.
// ---------------------------------------------------------------------------
__global__ __launch_bounds__(256) void gat_reduce(
    const float* __restrict__ part,    // [2,B,N,NHF]
    const float* __restrict__ dpart,   // [2,B,H,N]
    const float* __restrict__ biases,  // [H,FP]
    float* __restrict__ out)           // [B,N,NHF]
{
    int gid = blockIdx.x * 256 + threadIdx.x;
    int row = gid >> 6;                // [0, B*N)
    int q   = gid & 63;                // float4 index within 256 feats
    int b = row >> 11, n = row & (NN - 1);
    int h = q >> 4;

    const f32x4* p4 = (const f32x4*)part;
    f32x4 n0 = p4[(size_t)row * 64 + q];
    f32x4 n1 = p4[(size_t)NB * NN * 64 + (size_t)row * 64 + q];
    size_t didx = ((size_t)b * NH + h) * NN + n;
    float d = dpart[didx] + dpart[(size_t)NB * NH * NN + didx];
    float rcp = 1.0f / d;
    f32x4 bias4 = ((const f32x4*)biases)[q];
    f32x4 y;
    #pragma unroll
    for (int e = 0; e < 4; ++e) {
        float v = fmaf(n0[e] + n1[e], rcp, bias4[e]);
        y[e] = (v > 0.f) ? v : (__expf(v) - 1.0f);   // ELU
    }
    ((f32x4*)out)[(size_t)row * 64 + q] = y;
}

// ---------------------------------------------------------------------------
// Fallback single-pass kernel (R8, proven): used when d_ws is too small.
// ---------------------------------------------------------------------------
__global__ __launch_bounds__(256)
__attribute__((amdgpu_waves_per_eu(4, 4)))
void gat_attn(
    const float* __restrict__ adj, const short* __restrict__ featsT,
    const float* __restrict__ s_out, const float* __restrict__ s_in,
    const float* __restrict__ biases, float* __restrict__ out)
{
    __shared__ __align__(16) float adj_lds[2][4096];

    int blk = blockIdx.x;
    int b  = blk >> 7;
    int it = blk & 127;
    int i0 = it * 16;
    int tid = threadIdx.x;
    int h = tid >> 6;
    int lane = tid & 63;
    int r  = lane & 15;
    int jg = lane >> 4;

    const char* asrc[4];
    #pragma unroll
    for (int k = 0; k < 4; ++k) {
        int row = h * 4 + k;
        asrc[k] = (const char*)(adj + ((size_t)b * NN + i0 + row) * NN)
                  + ((lane ^ (row & 7)) << 4);
    }

#define STAGE(BUF, SC) do {                                                   \
        _Pragma("unroll")                                                     \
        for (int k = 0; k < 4; ++k)                                           \
            async16(asrc[k] + (size_t)(SC) * 1024,                            \
                    &adj_lds[BUF][(h * 4 + k) << 8]);                         \
    } while (0)

    STAGE(0, 0);

    float so = s_out[((size_t)b * NH + h) * NN + i0 + r];
    const float* sirow = s_in + ((size_t)b * NH + h) * NN + jg * 8;
    const short* vwave = featsT + (size_t)(b * NH + h) * NP * NN + jg * 512 + r * 8;
    int rsw = r & 7;
    int f0 = ((jg * 2)     ^ rsw) << 2;
    int f1 = ((jg * 2 + 1) ^ rsw) << 2;
    int rbase = r << 8;

    float bias_v[4];
    #pragma unroll
    for (int o = 0; o < 4; ++o) bias_v[o] = biases[h * NP + o * 16 + r];

    bf16x8 ones;
    #pragma unroll
    for (int e = 0; e < 8; ++e) ones[e] = (short)0x3F80;

    DRAIN_BARRIER();

    f32x4 acc[4] = {};
    f32x4 acc4 = {};

#define KSTEP(S, KS, Q0, Q1, V0, V1, V2, V3) do {                             \
        const float* ap = ab + rbase + (((S) * 16 + (KS) * 8) << 2);          \
        f32x4 a0 = *(const f32x4*)(ap + f0);                                  \
        f32x4 a1 = *(const f32x4*)(ap + f1);                                  \
        bf16x8 af;                                                            \
        _Pragma("unroll")                                                     \
        for (int e = 0; e < 8; ++e) {                                         \
            float av = (e < 4) ? a0[e] : a1[e - 4];                           \
            float sv = (e < 4) ? Q0[e] : Q1[e - 4];                           \
            float t = so + sv;                                                \
            float lr = fmaxf(t, 0.2f * t);                                    \
            float arg = fmaf(av, LOG2E, lr);                                  \
            float pe_ = exp2_fast(arg);                                       \
            float p = (av != 0.f) ? pe_ : 0.f;                                \
            __hip_bfloat16 hbv = __float2bfloat16(p);                         \
            af[e] = (short)__builtin_bit_cast(unsigned short, hbv);           \
        }                                                                     \
        acc[0] = __builtin_amdgcn_mfma_f32_16x16x32_bf16(af, V0, acc[0], 0, 0, 0); \
        acc[1] = __builtin_amdgcn_mfma_f32_16x16x32_bf16(af, V1, acc[1], 0, 0, 0); \
        acc[2] = __builtin_amdgcn_mfma_f32_16x16x32_bf16(af, V2, acc[2], 0, 0, 0); \
        acc[3] = __builtin_amdgcn_mfma_f32_16x16x32_bf16(af, V3, acc[3], 0, 0, 0); \
        acc4   = __builtin_amdgcn_mfma_f32_16x16x32_bf16(af, ones, acc4, 0, 0, 0); \
    } while (0)

#define SUB(SC, S) do {                                                       \
        const short* vp = vwave + (size_t)(((SC) * 32 + (S) * 8) << 9);       \
        bf16x8 v00 = *(const bf16x8*)(vp);                                    \
        bf16x8 v01 = *(const bf16x8*)(vp + 128);                              \
        bf16x8 v02 = *(const bf16x8*)(vp + 256);                              \
        bf16x8 v03 = *(const bf16x8*)(vp + 384);                              \
        bf16x8 v10 = *(const bf16x8*)(vp + 2048);                             \
        bf16x8 v11 = *(const bf16x8*)(vp + 2048 + 128);                       \
        bf16x8 v12 = *(const bf16x8*)(vp + 2048 + 256);                       \
        bf16x8 v13 = *(const bf16x8*)(vp + 2048 + 384);                       \
        const float* sip = sirow + (SC) * 256 + (S) * 64;                     \
        f32x4 q00 = *(const f32x4*)(sip);                                     \
        f32x4 q01 = *(const f32x4*)(sip + 4);                                 \
        f32x4 q10 = *(const f32x4*)(sip + 32);                                \
        f32x4 q11 = *(const f32x4*)(sip + 36);                                \
        KSTEP(S, 0, q00, q01, v00, v01, v02, v03);                            \
        KSTEP(S, 1, q10, q11, v10, v11, v12, v13);                            \
    } while (0)

    for (int sc = 0; sc < 8; ++sc) {
        int cur = sc & 1;
        const float* ab = &adj_lds[cur][0];
        SUB(sc, 0);
        if (sc < 7) STAGE(cur ^ 1, sc + 1);
        SUB(sc, 1);
        SUB(sc, 2);
        SUB(sc, 3);
        DRAIN_BARRIER();
    }
#undef SUB
#undef KSTEP
#undef STAGE

    #pragma unroll
    for (int reg = 0; reg < 4; ++reg) {
        int row = jg * 4 + reg;
        float rcp = 1.0f / acc4[reg];
        float* orow = out + ((size_t)b * NN + i0 + row) * NHF + h * NP;
        #pragma unroll
        for (int o = 0; o < 4; ++o) {
            float y = acc[o][reg] * rcp + bias_v[o];
            y = (y > 0.f) ? y : (__expf(y) - 1.0f);
            orow[o * 16 + r] = y;
        }
    }
}

extern "C" void kernel_launch(void* const* d_in, const int* in_sizes, int n_in,
                              void* d_out, int out_size, void* d_ws, size_t ws_size,
                              hipStream_t stream) {
    const float* x      = (const float*)d_in[0];  // node_feats [B,N,F]
    const float* adj    = (const float*)d_in[1];  // adjacency  [B,N,N]
    // d_in[2] = attn_mask -- NOT read; derived from adj (edge <=> adj != 0)
    const float* W      = (const float*)d_in[3];  // kernels    [H,F,FP]
    const float* biases = (const float*)d_in[4];  // [H,FP]
    const float* a_out  = (const float*)d_in[5];  // [H,FP]
    const float* a_in   = (const float*)d_in[6];  // [H,FP]
    float* out = (float*)d_out;

    char* ws = (char*)d_ws;
    short* featsT = (short*)ws;                                // 8 MB bf16, interleaved
    float* s_out  = (float*)(ws + 8388608);                    // 256 KB
    float* s_in   = (float*)(ws + 8388608 + 262144);           // 256 KB
    float* part   = (float*)(ws + 8912896);                    // 33.5 MB
    float* dpart  = (float*)(ws + 8912896 + 33554432);         // 512 KB
    const size_t need_split = 8912896ull + 33554432ull + 524288ull;

    gat_scores<<<256, 256, 0, stream>>>(x, W, a_out, a_in, s_out, s_in);
    gat_feats<<<NB * NH * (NN / 64), 256, 0, stream>>>(x, W, featsT);
    if (ws_size >= need_split) {
        gat_attn_part<<<NB * (NN / 16) * 2, 256, 0, stream>>>(adj, featsT, s_out, s_in, part, dpart);
        gat_reduce<<<NB * NN * NHF / 4 / 256, 256, 0, stream>>>(part, dpart, biases, out);
    } else {
        gat_attn<<<NB * (NN / 16), 256, 0, stream>>>(adj, featsT, s_out, s_in, biases, out);
    }
}

// Round 10
// 96.275 us; speedup vs baseline: 1.4862x; 1.4862x over previous
//
#include <hip/hip_runtime.h>
#include <hip/hip_bf16.h>

#define NB 8
#define NN 2048
#define NF 64      // in features
#define NP 64      // out features per head
#define NH 4
#define NHF 256    // NH*NP
#define LOG2E 1.4426950408889634f

typedef float f32x4 __attribute__((ext_vector_type(4)));
typedef short bf16x8 __attribute__((ext_vector_type(8)));
typedef short s16x4 __attribute__((ext_vector_type(4)));

// f32 -> bf16 bits, round-nearest-even
__device__ __forceinline__ short f2bf(float f) {
    unsigned u = __builtin_bit_cast(unsigned, f);
    unsigned r = (u + 0x7fffu + ((u >> 16) & 1u)) >> 16;
    return (short)r;
}

__device__ __forceinline__ float exp2_fast(float x) {
#if __has_builtin(__builtin_amdgcn_exp2f)
    return __builtin_amdgcn_exp2f(x);
#else
    float r;
    asm volatile("v_exp_f32 %0, %1\n\ts_nop 1" : "=v"(r) : "v"(x));
    return r;
#endif
}

__device__ __forceinline__ void async16(const void* g, void* l) {
    __builtin_amdgcn_global_load_lds(
        (const __attribute__((address_space(1))) void*)g,
        (__attribute__((address_space(3))) void*)l, 16, 0, 0);
}

// Full drain before barrier: LDS-DMA (global_load_lds) must complete before
// any wave crosses (R7 replay-race lesson).
#define DRAIN_BARRIER() do {                                                  \
        asm volatile("s_waitcnt vmcnt(0) lgkmcnt(0)" ::: "memory");           \
        __syncthreads();                                                      \
    } while (0)

// ---------------------------------------------------------------------------
// Kernel A1: s_out[b,h,n] = (x[b,n,:] . (W[h] @ a_out[h])) * LOG2E, same s_in.
// ---------------------------------------------------------------------------
__global__ __launch_bounds__(256) void gat_scores(
    const float* __restrict__ x, const float* __restrict__ W,
    const float* __restrict__ a_out, const float* __restrict__ a_in,
    float* __restrict__ s_out, float* __restrict__ s_in)
{
    __shared__ float co_lds[NH][NF];
    __shared__ float ci_lds[NH][NF];
    int tid = threadIdx.x;
    int h = tid >> 6, f = tid & 63;
    {
        float co = 0.f, ci = 0.f;
        const float* wrow = W + (h * NF + f) * NP;
        #pragma unroll 8
        for (int o = 0; o < NP; ++o) {
            float w = wrow[o];
            co = fmaf(w, a_out[h * NP + o], co);
            ci = fmaf(w, a_in[h * NP + o], ci);
        }
        co_lds[h][f] = co;
        ci_lds[h][f] = ci;
    }
    __syncthreads();
    int wid = tid >> 6, lane = tid & 63;
    float cov[NH], civ[NH];
    #pragma unroll
    for (int hh = 0; hh < NH; ++hh) { cov[hh] = co_lds[hh][lane]; civ[hh] = ci_lds[hh][lane]; }
    int base = blockIdx.x * 64 + wid * 16;     // global row in [0, B*N)
    for (int r = 0; r < 16; ++r) {
        int gn = base + r;
        float xv = x[(size_t)gn * NF + lane];
        #pragma unroll
        for (int hh = 0; hh < NH; ++hh) {
            float vo = xv * cov[hh];
            float vi = xv * civ[hh];
            #pragma unroll
            for (int s2 = 1; s2 < 64; s2 <<= 1) {
                vo += __shfl_xor(vo, s2, 64);
                vi += __shfl_xor(vi, s2, 64);
            }
            if (lane == 0) {
                int b = gn >> 11, n = gn & (NN - 1);
                s_out[((size_t)b * NH + hh) * NN + n] = vo * LOG2E;
                s_in [((size_t)b * NH + hh) * NN + n] = vi * LOG2E;
            }
        }
    }
}

// ---------------------------------------------------------------------------
// Kernel A2: featsT interleaved: element (feature o, node j) of head (b,h) at
// base(b,h) + (j>>3)*512 + o*8 + (j&7)  => V-frag loads are 256B-contiguous.
// ---------------------------------------------------------------------------
__global__ __launch_bounds__(256) void gat_feats(
    const float* __restrict__ x, const float* __restrict__ W,
    short* __restrict__ featsT)
{
    int blk = blockIdx.x;
    int nb = blk & 31;           // N/64 = 32
    int h  = (blk >> 5) & 3;
    int b  = blk >> 7;
    int tid = threadIdx.x, wid = tid >> 6, lane = tid & 63;
    int n0 = nb * 64 + wid * 16;
    int rA = lane & 15, g = lane >> 4;

    bf16x8 af[2];
    #pragma unroll
    for (int kk = 0; kk < 2; ++kk) {
        const float* xp = x + ((size_t)(b * NN) + n0 + rA) * NF + kk * 32 + g * 8;
        f32x4 x0 = *(const f32x4*)xp;
        f32x4 x1 = *(const f32x4*)(xp + 4);
        #pragma unroll
        for (int e = 0; e < 4; ++e) {
            af[kk][e]     = f2bf(x0[e]);
            af[kk][e + 4] = f2bf(x1[e]);
        }
    }
    f32x4 acc[4] = {};
    #pragma unroll
    for (int o = 0; o < 4; ++o) {
        #pragma unroll
        for (int kk = 0; kk < 2; ++kk) {
            bf16x8 bfv;
            #pragma unroll
            for (int e = 0; e < 8; ++e) {
                float wv = W[((size_t)h * NF + kk * 32 + g * 8 + e) * NP + o * 16 + rA];
                bfv[e] = f2bf(wv);
            }
            acc[o] = __builtin_amdgcn_mfma_f32_16x16x32_bf16(af[kk], bfv, acc[o], 0, 0, 0);
        }
    }
    size_t hb = (size_t)(b * NH + h) * NP * NN;
    int jq = n0 / 8 + (g >> 1);     // j>>3 for j = n0 + g*4
    int jr = (g & 1) * 4;           // j&7
    #pragma unroll
    for (int o = 0; o < 4; ++o) {
        s16x4 pk;
        pk[0] = f2bf(acc[o][0]);
        pk[1] = f2bf(acc[o][1]);
        pk[2] = f2bf(acc[o][2]);
        pk[3] = f2bf(acc[o][3]);
        *(s16x4*)(featsT + hb + (size_t)jq * 512 + (o * 16 + rA) * 8 + jr) = pk;
    }
}

// ---------------------------------------------------------------------------
// Kernel B: fused masked-softmax attention + PV (single-pass, R8 structure).
// Grid: B*(N/16) = 1024 blocks x 256 thr (4 waves = 4 heads, 16 i-rows).
// R10 changes vs R8:
//  (1) STAGE issued at END of phase (after all SUB V/si loads): vmcnt retires
//      in order, so a stage issued mid-phase forces every later V/si wait to
//      drain the HBM stage (~900cy x 3 SUBs/phase). At phase end it is waited
//      only once, at the barrier.
//  (2) XCD-aware block swizzle: blk = (bid&7)*128 + (bid>>3) puts exactly one
//      batch per XCD -> that batch's 1MB featsT slice stays L2-resident.
// ---------------------------------------------------------------------------
__global__ __launch_bounds__(256)
__attribute__((amdgpu_waves_per_eu(4, 4)))
void gat_attn(
    const float* __restrict__ adj,     // [B,N,N]
    const short* __restrict__ featsT,  // interleaved, see gat_feats
    const float* __restrict__ s_out,   // [B,H,N]  (prescaled by log2e)
    const float* __restrict__ s_in,    // [B,H,N]  (prescaled by log2e)
    const float* __restrict__ biases,  // [H,FP]
    float* __restrict__ out)           // [B,N,H*FP]
{
    __shared__ __align__(16) float adj_lds[2][4096];  // 2 x 16 KB (16 rows x 256 j)

    // XCD swizzle: grid 1024 = 8 XCD x 128; XCD x owns batch x entirely.
    int blk = ((blockIdx.x & 7) << 7) + (blockIdx.x >> 3);
    int b  = blk >> 7;            // 128 i-tiles per batch
    int it = blk & 127;
    int i0 = it * 16;
    int tid = threadIdx.x;
    int h = tid >> 6;             // wave = head (wave-uniform)
    int lane = tid & 63;
    int r  = lane & 15;           // A-frag row / B-frag col
    int jg = lane >> 4;

    // per-lane global source for the 4 rows this wave stages (row = h*4+k):
    // lane L fetches 16B block (L ^ (row&7)) of the row's 1024B super-chunk.
    const char* asrc[4];
    #pragma unroll
    for (int k = 0; k < 4; ++k) {
        int row = h * 4 + k;
        asrc[k] = (const char*)(adj + ((size_t)b * NN + i0 + row) * NN)
                  + ((lane ^ (row & 7)) << 4);
    }

#define STAGE(BUF, SC) do {                                                   \
        _Pragma("unroll")                                                     \
        for (int k = 0; k < 4; ++k)                                           \
            async16(asrc[k] + (size_t)(SC) * 1024,                            \
                    &adj_lds[BUF][(h * 4 + k) << 8]);                         \
    } while (0)

    // prologue: stage super-chunk 0 into buf 0
    STAGE(0, 0);

    float so = s_out[((size_t)b * NH + h) * NN + i0 + r];
    const float* sirow = s_in + ((size_t)b * NH + h) * NN + jg * 8;
    const short* vwave = featsT + (size_t)(b * NH + h) * NP * NN + jg * 512 + r * 8;
    int rsw = r & 7;
    int f0 = ((jg * 2)     ^ rsw) << 2;   // float offset of frag half 0 in 128B group
    int f1 = ((jg * 2 + 1) ^ rsw) << 2;   // float offset of frag half 1
    int rbase = r << 8;                   // row stride = 256 floats (1KB)

    float bias_v[4];
    #pragma unroll
    for (int o = 0; o < 4; ++o) bias_v[o] = biases[h * NP + o * 16 + r];

    bf16x8 ones;
    #pragma unroll
    for (int e = 0; e < 8; ++e) ones[e] = (short)0x3F80;   // bf16 1.0

    DRAIN_BARRIER();   // prologue stage fully landed in LDS

    f32x4 acc[4] = {};
    f32x4 acc4 = {};   // row-sum accumulator (denominator)

// one 16x32 P-subtile: 2 LDS adj reads + P-compute + 5 MFMA
#define KSTEP(S, KS, Q0, Q1, V0, V1, V2, V3) do {                             \
        const float* ap = ab + rbase + (((S) * 16 + (KS) * 8) << 2);          \
        f32x4 a0 = *(const f32x4*)(ap + f0);                                  \
        f32x4 a1 = *(const f32x4*)(ap + f1);                                  \
        bf16x8 af;                                                            \
        _Pragma("unroll")                                                     \
        for (int e = 0; e < 8; ++e) {                                         \
            float av = (e < 4) ? a0[e] : a1[e - 4];                           \
            float sv = (e < 4) ? Q0[e] : Q1[e - 4];                           \
            float t = so + sv;                                                \
            float lr = fmaxf(t, 0.2f * t);                                    \
            float arg = fmaf(av, LOG2E, lr);                                  \
            float pe_ = exp2_fast(arg);                                       \
            float p = (av != 0.f) ? pe_ : 0.f;                                \
            __hip_bfloat16 hbv = __float2bfloat16(p);                         \
            af[e] = (short)__builtin_bit_cast(unsigned short, hbv);           \
        }                                                                     \
        acc[0] = __builtin_amdgcn_mfma_f32_16x16x32_bf16(af, V0, acc[0], 0, 0, 0); \
        acc[1] = __builtin_amdgcn_mfma_f32_16x16x32_bf16(af, V1, acc[1], 0, 0, 0); \
        acc[2] = __builtin_amdgcn_mfma_f32_16x16x32_bf16(af, V2, acc[2], 0, 0, 0); \
        acc[3] = __builtin_amdgcn_mfma_f32_16x16x32_bf16(af, V3, acc[3], 0, 0, 0); \
        acc4   = __builtin_amdgcn_mfma_f32_16x16x32_bf16(af, ones, acc4, 0, 0, 0); \
    } while (0)

// one 64-j sub-chunk: load V (8x16B) + si (4x16B), then 2 KSTEPs
#define SUB(SC, S) do {                                                       \
        const short* vp = vwave + (size_t)(((SC) * 32 + (S) * 8) << 9);       \
        bf16x8 v00 = *(const bf16x8*)(vp);                                    \
        bf16x8 v01 = *(const bf16x8*)(vp + 128);                              \
        bf16x8 v02 = *(const bf16x8*)(vp + 256);                              \
        bf16x8 v03 = *(const bf16x8*)(vp + 384);                              \
        bf16x8 v10 = *(const bf16x8*)(vp + 2048);                             \
        bf16x8 v11 = *(const bf16x8*)(vp + 2048 + 128);                       \
        bf16x8 v12 = *(const bf16x8*)(vp + 2048 + 256);                       \
        bf16x8 v13 = *(const bf16x8*)(vp + 2048 + 384);                       \
        const float* sip = sirow + (SC) * 256 + (S) * 64;                     \
        f32x4 q00 = *(const f32x4*)(sip);                                     \
        f32x4 q01 = *(const f32x4*)(sip + 4);                                 \
        f32x4 q10 = *(const f32x4*)(sip + 32);                                \
        f32x4 q11 = *(const f32x4*)(sip + 36);                                \
        KSTEP(S, 0, q00, q01, v00, v01, v02, v03);                            \
        KSTEP(S, 1, q10, q11, v10, v11, v12, v13);                            \
    } while (0)

    for (int sc = 0; sc < 8; ++sc) {
        int cur = sc & 1;
        const float* ab = &adj_lds[cur][0];
        SUB(sc, 0);
        SUB(sc, 1);
        SUB(sc, 2);
        SUB(sc, 3);
        // stage next super-chunk LAST: all consumer loads are older in the
        // vmcnt FIFO, so their counted waits never drain this HBM stage.
        if (sc < 7) STAGE(cur ^ 1, sc + 1);
        DRAIN_BARRIER();   // single exposed wait for the stage, at the barrier
    }
#undef SUB
#undef KSTEP
#undef STAGE

    // epilogue: denominator for row (jg*4+reg) is acc4[reg] in every lane of
    // the matching group (all-ones B => every column holds the row sum).
    #pragma unroll
    for (int reg = 0; reg < 4; ++reg) {
        int row = jg * 4 + reg;                  // D row = (lane>>4)*4 + reg
        float rcp = 1.0f / acc4[reg];
        float* orow = out + ((size_t)b * NN + i0 + row) * NHF + h * NP;
        #pragma unroll
        for (int o = 0; o < 4; ++o) {
            float y = acc[o][reg] * rcp + bias_v[o];
            y = (y > 0.f) ? y : (__expf(y) - 1.0f);   // ELU
            orow[o * 16 + r] = y;
        }
    }
}

extern "C" void kernel_launch(void* const* d_in, const int* in_sizes, int n_in,
                              void* d_out, int out_size, void* d_ws, size_t ws_size,
                              hipStream_t stream) {
    const float* x      = (const float*)d_in[0];  // node_feats [B,N,F]
    const float* adj    = (const float*)d_in[1];  // adjacency  [B,N,N]
    // d_in[2] = attn_mask -- NOT read; derived from adj (edge <=> adj != 0)
    const float* W      = (const float*)d_in[3];  // kernels    [H,F,FP]
    const float* biases = (const float*)d_in[4];  // [H,FP]
    const float* a_out  = (const float*)d_in[5];  // [H,FP]
    const float* a_in   = (const float*)d_in[6];  // [H,FP]
    float* out = (float*)d_out;

    char* ws = (char*)d_ws;
    short* featsT = (short*)ws;                                // 8 MB bf16, interleaved
    float* s_out  = (float*)(ws + 8388608);                    // 256 KB
    float* s_in   = (float*)(ws + 8388608 + 262144);           // 256 KB

    gat_scores<<<256, 256, 0, stream>>>(x, W, a_out, a_in, s_out, s_in);
    gat_feats<<<NB * NH * (NN / 64), 256, 0, stream>>>(x, W, featsT);
    gat_attn<<<NB * (NN / 16), 256, 0, stream>>>(adj, featsT, s_out, s_in, biases, out);
}